// Round 2
// baseline (406.313 us; speedup 1.0000x reference)
//
#include <hip/hip_runtime.h>

typedef __attribute__((ext_vector_type(8))) __bf16 bf16x8;
typedef __attribute__((ext_vector_type(4))) float f32x4;

#define IMG 112
#define CDIM 128
#define NH 4
#define WS7 7
#define NTOK 49
#define SHF 3

__device__ __forceinline__ ushort f2bf(float f) {
  uint u = __float_as_uint(f);
  u += 0x7FFFu + ((u >> 16) & 1u);
  return (ushort)(u >> 16);
}
__device__ __forceinline__ int d7(int n) { return (n * 9363) >> 16; }  // n/7 for n<=63

// ---------------- prep: bf16 weights (+q scale fold), biases, rpb table ----------------
__global__ void prep_kernel(const float* __restrict__ Wq, const float* __restrict__ Wk,
                            const float* __restrict__ Wv, const float* __restrict__ Wp,
                            const float* __restrict__ bq, const float* __restrict__ bk,
                            const float* __restrict__ bv, const float* __restrict__ bp,
                            const float* __restrict__ tbl,
                            ushort* __restrict__ wW, float* __restrict__ wB,
                            float* __restrict__ wR) {
  int t = blockIdx.x * 256 + threadIdx.x;
  const float SC = 0.17677669529663687f;  // 32^-0.5
  if (t < 65536) {
    int m = t >> 14, e = t & 16383;
    const float* W = (m == 0) ? Wq : (m == 1) ? Wk : (m == 2) ? Wv : Wp;
    float v = W[e];
    if (m == 0) v *= SC;
    wW[t] = f2bf(v);
  } else if (t < 66048) {
    int t2 = t - 65536;
    int m = t2 >> 7, e = t2 & 127;
    const float* B = (m == 0) ? bq : (m == 1) ? bk : (m == 2) ? bv : bp;
    float v = B[e];
    if (m == 0) v *= SC;
    wB[t2] = v;
  } else if (t < 75652) {
    int t3 = t - 66048;
    int h = t3 / 2401, r = t3 % 2401;
    int n = r / 49, m = r % 49;
    int rn = n / 7, cn = n % 7, rm = m / 7, cm = m % 7;
    int idx = (rn - rm + 6) * 13 + (cn - cm + 6);
    wR[t3] = tbl[idx * NH + h];
  }
}

// LDS layout (ushort units):
//  [0, 9216)      : x_s[49][136] (A/B)  |  p_s[2][64][72] (attn)  |  o_s[49][136] (proj in)
//  [9216, 15880)  : q_s[49][136]
//  [15880, 22544) : k_s[49][136]
//  [22544, 31760) : vT[128][72]   (v transposed: [channel][token])
__global__ __launch_bounds__(512) void swin_kernel(
    const float* __restrict__ X, const ushort* __restrict__ wW,
    const float* __restrict__ wB, const float* __restrict__ wR,
    float* __restrict__ out) {
  __shared__ ushort lds[31760];
  const int tid = threadIdx.x;
  const int wv = tid >> 6;     // 0..7
  const int lane = tid & 63;
  const int lr = lane & 15;
  const int kg = lane >> 4;

  const int blk = blockIdx.x;
  const int b = blk >> 8;
  const int wid = blk & 255;
  const int wi = wid >> 4, wj = wid & 15;
  const size_t gBase = (size_t)b * (IMG * IMG * CDIM);

  // ---------------- Phase A: gather rolled window, f32 -> bf16 ----------------
  for (int idx = tid; idx < NTOK * 32; idx += 512) {
    int row = idx >> 5, q4 = idx & 31;
    int r = d7(row), c = row - r * 7;
    int gh = wi * 7 + r + SHF; if (gh >= IMG) gh -= IMG;
    int gw = wj * 7 + c + SHF; if (gw >= IMG) gw -= IMG;
    const float4* src = reinterpret_cast<const float4*>(X + gBase + ((size_t)gh * IMG + gw) * CDIM);
    float4 v = src[q4];
    ushort4 h4;
    h4.x = f2bf(v.x); h4.y = f2bf(v.y); h4.z = f2bf(v.z); h4.w = f2bf(v.w);
    *reinterpret_cast<ushort4*>(&lds[row * 136 + q4 * 4]) = h4;
  }
  __syncthreads();

  // ---------------- Phase B: QKV projections ----------------
  // wave (wq = wv&3) owns output channels [wq*32, wq*32+32); (mh = wv>>2) owns rows [mh*32, mh*32+32)
  {
    const int wq = wv & 3, mh = wv >> 2;
    const int c0 = wq * 32;
    for (int pj = 0; pj < 3; ++pj) {
      const ushort* W = wW + pj * 16384;
      f32x4 acc[2][2] = {};
      for (int kk = 0; kk < 4; ++kk) {
        bf16x8 a[2], bb[2];
#pragma unroll
        for (int mt = 0; mt < 2; ++mt) {
          int row = mh * 32 + mt * 16 + lr; if (row > 48) row = 48;
          a[mt] = *reinterpret_cast<const bf16x8*>(&lds[row * 136 + kk * 32 + kg * 8]);
        }
#pragma unroll
        for (int nt = 0; nt < 2; ++nt) {
          int co = c0 + nt * 16 + lr;
          bb[nt] = *reinterpret_cast<const bf16x8*>(&W[co * 128 + kk * 32 + kg * 8]);
        }
#pragma unroll
        for (int mt = 0; mt < 2; ++mt)
#pragma unroll
          for (int nt = 0; nt < 2; ++nt)
            acc[mt][nt] = __builtin_amdgcn_mfma_f32_16x16x32_bf16(a[mt], bb[nt], acc[mt][nt], 0, 0, 0);
      }
#pragma unroll
      for (int nt = 0; nt < 2; ++nt) {
        int co = c0 + nt * 16 + lr;
        float bias = wB[pj * 128 + co];
#pragma unroll
        for (int mt = 0; mt < 2; ++mt) {
          int rb = mh * 32 + mt * 16 + kg * 4;
          if (pj == 2) {
            ushort4 h4;
            h4.x = f2bf(acc[mt][nt][0] + bias);
            h4.y = f2bf(acc[mt][nt][1] + bias);
            h4.z = f2bf(acc[mt][nt][2] + bias);
            h4.w = f2bf(acc[mt][nt][3] + bias);
            *reinterpret_cast<ushort4*>(&lds[22544 + co * 72 + rb]) = h4;
          } else {
            const int base = (pj == 0) ? 9216 : 15880;
#pragma unroll
            for (int i = 0; i < 4; ++i) {
              int row = rb + i;
              if (row < 49) lds[base + row * 136 + co] = f2bf(acc[mt][nt][i] + bias);
            }
          }
        }
      }
    }
  }
  __syncthreads();

  // ---------------- Attention: 2 passes x 2 heads; wave = (hloc = wv>>2, mq = wv&3) ----------------
  // Each wave owns P rows [mq*16, mq*16+16) of head-buffer hloc -> P-write->PV is a
  // within-wave LDS dependence, no __syncthreads needed inside the pass loop.
  const int hloc = wv >> 2;  // head within pass / p_s buffer
  const int mq = wv & 3;     // row quarter (16 rows)
  const bool edgeH = (wi == 15), edgeW = (wj == 15);
  f32x4 oacc[2][2] = {};  // [pass][dt]

#pragma unroll
  for (int pass = 0; pass < 2; ++pass) {
    const int h = pass * 2 + hloc;
    // --- S = q k^T (K=32, one mfma step) ---
    f32x4 s[4] = {};
    {
      bf16x8 a, bb[4];
      {
        int row = mq * 16 + lr; if (row > 48) row = 48;
        a = *reinterpret_cast<const bf16x8*>(&lds[9216 + row * 136 + h * 32 + kg * 8]);
      }
#pragma unroll
      for (int nt = 0; nt < 4; ++nt) {
        int row = nt * 16 + lr; if (row > 48) row = 48;
        bb[nt] = *reinterpret_cast<const bf16x8*>(&lds[15880 + row * 136 + h * 32 + kg * 8]);
      }
#pragma unroll
      for (int nt = 0; nt < 4; ++nt)
        s[nt] = __builtin_amdgcn_mfma_f32_16x16x32_bf16(a, bb[nt], s[nt], 0, 0, 0);
    }
    // --- rpb + shift mask + softmax + write P (bf16) ---
    int mvals[4], ridm[4]; bool mvalid[4];
#pragma unroll
    for (int nt = 0; nt < 4; ++nt) {
      int m = nt * 16 + lr;
      mvals[nt] = m; mvalid[nt] = (m < NTOK);
      int rm = d7(m), cm = m - rm * 7;
      ridm[nt] = (edgeH ? (rm < 4 ? 3 : 6) : 0) + (edgeW ? (cm < 4 ? 1 : 2) : 0);
    }
#pragma unroll
    for (int i = 0; i < 4; ++i) {
      int n = mq * 16 + kg * 4 + i;
      bool nvalid = (n < NTOK);
      int rn = d7(n), cn = n - rn * 7;
      int ridn = (edgeH ? (rn < 4 ? 3 : 6) : 0) + (edgeW ? (cn < 4 ? 1 : 2) : 0);
      float l0 = s[0][i], l1 = s[1][i], l2 = s[2][i], l3 = s[3][i];
      if (nvalid) {
        if (mvalid[0]) { l0 += wR[(h * 49 + n) * 49 + mvals[0]]; if (ridn != ridm[0]) l0 -= 100.0f; }
        if (mvalid[1]) { l1 += wR[(h * 49 + n) * 49 + mvals[1]]; if (ridn != ridm[1]) l1 -= 100.0f; }
        if (mvalid[2]) { l2 += wR[(h * 49 + n) * 49 + mvals[2]]; if (ridn != ridm[2]) l2 -= 100.0f; }
        if (mvalid[3]) { l3 += wR[(h * 49 + n) * 49 + mvals[3]]; if (ridn != ridm[3]) l3 -= 100.0f; }
      }
      if (!mvalid[0]) l0 = -1e30f;
      if (!mvalid[1]) l1 = -1e30f;
      if (!mvalid[2]) l2 = -1e30f;
      if (!mvalid[3]) l3 = -1e30f;
      float mx = fmaxf(fmaxf(l0, l1), fmaxf(l2, l3));
      mx = fmaxf(mx, __shfl_xor(mx, 1));
      mx = fmaxf(mx, __shfl_xor(mx, 2));
      mx = fmaxf(mx, __shfl_xor(mx, 4));
      mx = fmaxf(mx, __shfl_xor(mx, 8));
      float e0 = __expf(l0 - mx), e1 = __expf(l1 - mx), e2 = __expf(l2 - mx), e3 = __expf(l3 - mx);
      float sum = e0 + e1 + e2 + e3;
      sum += __shfl_xor(sum, 1);
      sum += __shfl_xor(sum, 2);
      sum += __shfl_xor(sum, 4);
      sum += __shfl_xor(sum, 8);
      float inv = 1.0f / sum;
      int pb = hloc * 4608 + n * 72;
      lds[pb + 0 + lr] = f2bf(e0 * inv);
      lds[pb + 16 + lr] = f2bf(e1 * inv);
      lds[pb + 32 + lr] = f2bf(e2 * inv);
      lds[pb + 48 + lr] = f2bf(e3 * inv);
    }
    // --- O += P v ---  (reads only this wave's own P rows: no barrier needed)
#pragma unroll
    for (int kk = 0; kk < 2; ++kk) {
      bf16x8 a, bv2[2];
      {
        int row = mq * 16 + lr;
        a = *reinterpret_cast<const bf16x8*>(&lds[hloc * 4608 + row * 72 + kk * 32 + kg * 8]);
      }
#pragma unroll
      for (int dt = 0; dt < 2; ++dt) {
        int d = h * 32 + dt * 16 + lr;
        bv2[dt] = *reinterpret_cast<const bf16x8*>(&lds[22544 + d * 72 + kk * 32 + kg * 8]);
      }
#pragma unroll
      for (int dt = 0; dt < 2; ++dt)
        oacc[pass][dt] = __builtin_amdgcn_mfma_f32_16x16x32_bf16(a, bv2[dt], oacc[pass][dt], 0, 0, 0);
    }
  }
  __syncthreads();  // all PV reads of p_s done before o_s overwrites region [0,9216)

  // ---------------- write attention output to o_s ----------------
#pragma unroll
  for (int pass = 0; pass < 2; ++pass) {
    int h = pass * 2 + hloc;
    int rb = mq * 16 + kg * 4;
#pragma unroll
    for (int dt = 0; dt < 2; ++dt) {
      int col = h * 32 + dt * 16 + lr;
#pragma unroll
      for (int i = 0; i < 4; ++i) {
        int row = rb + i;
        if (row < NTOK) lds[row * 136 + col] = f2bf(oacc[pass][dt][i]);
      }
    }
  }
  __syncthreads();

  // ---------------- Phase E: output projection + scatter (un-roll) ----------------
  {
    const ushort* Wp = wW + 3 * 16384;
    const int wq = wv & 3, mh = wv >> 2;
    const int c0 = wq * 32;
    f32x4 acc[2][2] = {};
    for (int kk = 0; kk < 4; ++kk) {
      bf16x8 a[2], bb[2];
#pragma unroll
      for (int mt = 0; mt < 2; ++mt) {
        int row = mh * 32 + mt * 16 + lr; if (row > 48) row = 48;
        a[mt] = *reinterpret_cast<const bf16x8*>(&lds[row * 136 + kk * 32 + kg * 8]);
      }
#pragma unroll
      for (int nt = 0; nt < 2; ++nt) {
        int co = c0 + nt * 16 + lr;
        bb[nt] = *reinterpret_cast<const bf16x8*>(&Wp[co * 128 + kk * 32 + kg * 8]);
      }
#pragma unroll
      for (int mt = 0; mt < 2; ++mt)
#pragma unroll
        for (int nt = 0; nt < 2; ++nt)
          acc[mt][nt] = __builtin_amdgcn_mfma_f32_16x16x32_bf16(a[mt], bb[nt], acc[mt][nt], 0, 0, 0);
    }
    float bp0 = wB[384 + c0 + lr];
    float bp1 = wB[384 + c0 + 16 + lr];
#pragma unroll
    for (int mt = 0; mt < 2; ++mt) {
      int rb = mh * 32 + mt * 16 + kg * 4;
#pragma unroll
      for (int i = 0; i < 4; ++i) {
        int n = rb + i;
        if (n < NTOK) {
          int r = d7(n), c = n - r * 7;
          int gh = wi * 7 + r + SHF; if (gh >= IMG) gh -= IMG;
          int gw = wj * 7 + c + SHF; if (gw >= IMG) gw -= IMG;
          float* dst = out + gBase + ((size_t)gh * IMG + gw) * CDIM;
          dst[c0 + lr] = acc[mt][0][i] + bp0;
          dst[c0 + 16 + lr] = acc[mt][1][i] + bp1;
        }
      }
    }
  }
}

extern "C" void kernel_launch(void* const* d_in, const int* in_sizes, int n_in,
                              void* d_out, int out_size, void* d_ws, size_t ws_size,
                              hipStream_t stream) {
  const float* X = (const float*)d_in[0];
  const float* Wq = (const float*)d_in[3];
  const float* Wk = (const float*)d_in[4];
  const float* Wv = (const float*)d_in[5];
  const float* Wp = (const float*)d_in[6];
  const float* bq = (const float*)d_in[7];
  const float* bk = (const float*)d_in[8];
  const float* bv = (const float*)d_in[9];
  const float* bp = (const float*)d_in[10];
  const float* tbl = (const float*)d_in[11];

  ushort* wW = (ushort*)d_ws;                            // 4 x [128][128] bf16 = 131072 B
  float* wB = (float*)((char*)d_ws + 131072);            // 4 x [128] f32   = 2048 B
  float* wR = (float*)((char*)d_ws + 131072 + 2048);     // [4][49][49] f32 = 38416 B

  prep_kernel<<<dim3(296), dim3(256), 0, stream>>>(Wq, Wk, Wv, Wp, bq, bk, bv, bp, tbl, wW, wB, wR);
  swin_kernel<<<dim3(8192), dim3(512), 0, stream>>>(X, wW, wB, wR, (float*)d_out);
}

// Round 3
// 358.359 us; speedup vs baseline: 1.1338x; 1.1338x over previous
//
#include <hip/hip_runtime.h>

typedef __attribute__((ext_vector_type(8))) __bf16 bf16x8;
typedef __attribute__((ext_vector_type(4))) float f32x4;

#define IMG 112
#define SHF 3

__device__ __forceinline__ ushort f2bf(float f) {
  return __builtin_bit_cast(unsigned short, static_cast<__bf16>(f));
}
__device__ __forceinline__ int d7(int n) { return (n * 9363) >> 16; }  // n/7 for n<=63

// ---------------- prep: bf16 weights (+q scale fold), biases, rpb+mask table ----------------
// wRM[cls][h][64 qt][64 kt]: rpb + (-100 shift mask) + (-1e30 for kt>=49 pad); 0 for qt>=49.
__global__ void prep_kernel(const float* __restrict__ Wq, const float* __restrict__ Wk,
                            const float* __restrict__ Wv, const float* __restrict__ Wp,
                            const float* __restrict__ bq, const float* __restrict__ bk,
                            const float* __restrict__ bv, const float* __restrict__ bp,
                            const float* __restrict__ tbl,
                            ushort* __restrict__ wW, float* __restrict__ wB,
                            float* __restrict__ wRM) {
  int t = blockIdx.x * 256 + threadIdx.x;
  const float SC = 0.17677669529663687f;  // 32^-0.5
  if (t < 65536) {
    int m = t >> 14, e = t & 16383;
    const float* W = (m == 0) ? Wq : (m == 1) ? Wk : (m == 2) ? Wv : Wp;
    float v = W[e];
    if (m == 0) v *= SC;
    wW[t] = f2bf(v);
  } else if (t < 66048) {
    int t2 = t - 65536;
    int m = t2 >> 7, e = t2 & 127;
    const float* B = (m == 0) ? bq : (m == 1) ? bk : (m == 2) ? bv : bp;
    float v = B[e];
    if (m == 0) v *= SC;
    wB[t2] = v;
  } else if (t < 131584) {
    int t3 = t - 66048;  // [0, 65536)
    int cls = t3 >> 14;
    int r = t3 & 16383;
    int h = r >> 12;
    int rr = r & 4095;
    int qt = rr >> 6, kt = rr & 63;
    float v;
    if (qt >= 49) v = 0.0f;
    else if (kt >= 49) v = -1e30f;
    else {
      int rq = qt / 7, cq = qt % 7, rk = kt / 7, ck = kt % 7;
      v = tbl[((rq - rk + 6) * 13 + (cq - ck + 6)) * 4 + h];
      int eH = (cls >> 1) & 1, eW = cls & 1;
      int ridq = (eH ? (rq < 4 ? 3 : 6) : 0) + (eW ? (cq < 4 ? 1 : 2) : 0);
      int ridk = (eH ? (rk < 4 ? 3 : 6) : 0) + (eW ? (ck < 4 ? 1 : 2) : 0);
      if (ridq != ridk) v -= 100.0f;
    }
    wRM[t3] = v;
  }
}

// LDS layout (ushort units):
//  [0, 9216)      : x_s[49][136] (A/B)  |  p_s[2][64][72] (attn)
//  [9216, 15880)  : q_s[49][136]  (aliased as o_s[49][136] after attn; wave-private rows)
//  [15880, 22544) : k_s[49][136]
//  [22544, 31760) : vT[128][72]   (v transposed: [channel][token])
#define PS 0
#define QS 9216
#define KS 15880
#define VT 22544

__global__ __launch_bounds__(512, 4) void swin_kernel(
    const float* __restrict__ X, const ushort* __restrict__ wW,
    const float* __restrict__ wB, const float* __restrict__ wRM,
    float* __restrict__ out) {
  __shared__ ushort lds[31760];
  const int tid = threadIdx.x;
  const int wv = tid >> 6;  // 0..7
  const int lane = tid & 63;
  const int lr = lane & 15;
  const int kg = lane >> 4;

  const int blk = blockIdx.x;
  const int b = blk >> 8;
  const int wid = blk & 255;
  const int wi = wid >> 4, wj = wid & 15;
  const size_t gBase = (size_t)b * (IMG * IMG * 128);

  // ---------------- Phase A: gather rolled window, f32 -> bf16 ----------------
  for (int idx = tid; idx < 49 * 32; idx += 512) {
    int row = idx >> 5, q4 = idx & 31;
    int r = d7(row), c = row - r * 7;
    int gh = wi * 7 + r + SHF; if (gh >= IMG) gh -= IMG;
    int gw = wj * 7 + c + SHF; if (gw >= IMG) gw -= IMG;
    float4 v = reinterpret_cast<const float4*>(X + gBase + ((size_t)gh * IMG + gw) * 128)[q4];
    ushort4 h4 = { f2bf(v.x), f2bf(v.y), f2bf(v.z), f2bf(v.w) };
    *reinterpret_cast<ushort4*>(&lds[PS + row * 136 + q4 * 4]) = h4;
  }
  __syncthreads();

  // ---------------- Phase B: QKV projections (q,k swapped -> vector writes) ----------------
  const int wc = wv & 3, wt = wv >> 2;
  const int c0 = wc * 32, t0 = wt * 32;
  {
    for (int pj = 0; pj < 2; ++pj) {  // q, k: D[co][tok]
      const ushort* W = wW + pj * 16384;
      f32x4 acc[2][2] = {};
      for (int kk = 0; kk < 4; ++kk) {
        bf16x8 aw[2], bx[2];
#pragma unroll
        for (int mt = 0; mt < 2; ++mt)
          aw[mt] = *reinterpret_cast<const bf16x8*>(&W[(c0 + mt * 16 + lr) * 128 + kk * 32 + kg * 8]);
#pragma unroll
        for (int nt = 0; nt < 2; ++nt) {
          int tok = t0 + nt * 16 + lr; if (tok > 48) tok = 48;
          bx[nt] = *reinterpret_cast<const bf16x8*>(&lds[PS + tok * 136 + kk * 32 + kg * 8]);
        }
#pragma unroll
        for (int mt = 0; mt < 2; ++mt)
#pragma unroll
          for (int nt = 0; nt < 2; ++nt)
            acc[mt][nt] = __builtin_amdgcn_mfma_f32_16x16x32_bf16(aw[mt], bx[nt], acc[mt][nt], 0, 0, 0);
      }
      const int sb = (pj == 0) ? QS : KS;
#pragma unroll
      for (int mt = 0; mt < 2; ++mt) {
        float4 b4 = *reinterpret_cast<const float4*>(&wB[pj * 128 + c0 + mt * 16 + kg * 4]);
#pragma unroll
        for (int nt = 0; nt < 2; ++nt) {
          int tok = t0 + nt * 16 + lr;
          if (tok < 49) {
            ushort4 h4 = { f2bf(acc[mt][nt][0] + b4.x), f2bf(acc[mt][nt][1] + b4.y),
                           f2bf(acc[mt][nt][2] + b4.z), f2bf(acc[mt][nt][3] + b4.w) };
            *reinterpret_cast<ushort4*>(&lds[sb + tok * 136 + c0 + mt * 16 + kg * 4]) = h4;
          }
        }
      }
    }
    {  // v: D[tok][co] -> vT[co][tok] vector writes
      const ushort* W = wW + 2 * 16384;
      f32x4 acc[2][2] = {};
      for (int kk = 0; kk < 4; ++kk) {
        bf16x8 ax[2], bw[2];
#pragma unroll
        for (int mt = 0; mt < 2; ++mt) {
          int tok = t0 + mt * 16 + lr; if (tok > 48) tok = 48;
          ax[mt] = *reinterpret_cast<const bf16x8*>(&lds[PS + tok * 136 + kk * 32 + kg * 8]);
        }
#pragma unroll
        for (int nt = 0; nt < 2; ++nt)
          bw[nt] = *reinterpret_cast<const bf16x8*>(&W[(c0 + nt * 16 + lr) * 128 + kk * 32 + kg * 8]);
#pragma unroll
        for (int mt = 0; mt < 2; ++mt)
#pragma unroll
          for (int nt = 0; nt < 2; ++nt)
            acc[mt][nt] = __builtin_amdgcn_mfma_f32_16x16x32_bf16(ax[mt], bw[nt], acc[mt][nt], 0, 0, 0);
      }
#pragma unroll
      for (int nt = 0; nt < 2; ++nt) {
        float bias = wB[256 + c0 + nt * 16 + lr];
#pragma unroll
        for (int mt = 0; mt < 2; ++mt) {
          ushort4 h4 = { f2bf(acc[mt][nt][0] + bias), f2bf(acc[mt][nt][1] + bias),
                         f2bf(acc[mt][nt][2] + bias), f2bf(acc[mt][nt][3] + bias) };
          *reinterpret_cast<ushort4*>(&lds[VT + (c0 + nt * 16 + lr) * 72 + t0 + mt * 16 + kg * 4]) = h4;
        }
      }
    }
  }
  __syncthreads();

  // ---------------- Attention: swapped QK^T, lane-local softmax rows ----------------
  const int hloc = wv >> 2, mq = wv & 3;
  const int qt = mq * 16 + lr;            // this lane's query token (col of D)
  const int qtc = qt > 48 ? 48 : qt;
  const int cls = ((wi == 15) ? 2 : 0) + ((wj == 15) ? 1 : 0);
  f32x4 oacc[2][2] = {};
#pragma unroll
  for (int pass = 0; pass < 2; ++pass) {
    const int h = pass * 2 + hloc;
    // S^T = K Q^T : D[kt][qt]
    f32x4 s[4] = {};
    {
      bf16x8 bq = *reinterpret_cast<const bf16x8*>(&lds[QS + qtc * 136 + h * 32 + kg * 8]);
#pragma unroll
      for (int at = 0; at < 4; ++at) {
        int kt = at * 16 + lr; if (kt > 48) kt = 48;
        bf16x8 ak = *reinterpret_cast<const bf16x8*>(&lds[KS + kt * 136 + h * 32 + kg * 8]);
        s[at] = __builtin_amdgcn_mfma_f32_16x16x32_bf16(ak, bq, s[at], 0, 0, 0);
      }
    }
    // rpb + mask (precomputed) + softmax over kt (16 in-lane + 2 shfl)
    const float* rp = wRM + (((size_t)cls * 4 + h) * 64 + qt) * 64;
    float mx = -3.0e38f;
#pragma unroll
    for (int at = 0; at < 4; ++at) {
      float4 r4 = *reinterpret_cast<const float4*>(&rp[at * 16 + kg * 4]);
      s[at][0] += r4.x; s[at][1] += r4.y; s[at][2] += r4.z; s[at][3] += r4.w;
      mx = fmaxf(mx, fmaxf(fmaxf(s[at][0], s[at][1]), fmaxf(s[at][2], s[at][3])));
    }
    mx = fmaxf(mx, __shfl_xor(mx, 16));
    mx = fmaxf(mx, __shfl_xor(mx, 32));
    float sum = 0.0f;
#pragma unroll
    for (int at = 0; at < 4; ++at) {
#pragma unroll
      for (int i = 0; i < 4; ++i) {
        float e = __expf(s[at][i] - mx);
        s[at][i] = e; sum += e;
      }
    }
    sum += __shfl_xor(sum, 16);
    sum += __shfl_xor(sum, 32);
    float inv = 1.0f / sum;
    const int pb = PS + hloc * 4608 + qt * 72;
#pragma unroll
    for (int at = 0; at < 4; ++at) {
      ushort4 p4 = { f2bf(s[at][0] * inv), f2bf(s[at][1] * inv),
                     f2bf(s[at][2] * inv), f2bf(s[at][3] * inv) };
      *reinterpret_cast<ushort4*>(&lds[pb + at * 16 + kg * 4]) = p4;
    }
    // O^T = V^T P^T : D[d][qt]  (reads only this wave's own P rows: no barrier)
#pragma unroll
    for (int kk = 0; kk < 2; ++kk) {
      bf16x8 bp = *reinterpret_cast<const bf16x8*>(&lds[pb + kk * 32 + kg * 8]);
#pragma unroll
      for (int mt = 0; mt < 2; ++mt) {
        bf16x8 av = *reinterpret_cast<const bf16x8*>(&lds[VT + (h * 32 + mt * 16 + lr) * 72 + kk * 32 + kg * 8]);
        oacc[pass][mt] = __builtin_amdgcn_mfma_f32_16x16x32_bf16(av, bp, oacc[pass][mt], 0, 0, 0);
      }
    }
  }

  // O -> o_s (aliased on q_s; wave-private rows so no barrier needed before)
#pragma unroll
  for (int pass = 0; pass < 2; ++pass) {
#pragma unroll
    for (int mt = 0; mt < 2; ++mt) {
      if (qt < 49) {
        ushort4 h4 = { f2bf(oacc[pass][mt][0]), f2bf(oacc[pass][mt][1]),
                       f2bf(oacc[pass][mt][2]), f2bf(oacc[pass][mt][3]) };
        *reinterpret_cast<ushort4*>(&lds[QS + qt * 136 + (pass * 2 + hloc) * 32 + mt * 16 + kg * 4]) = h4;
      }
    }
  }
  __syncthreads();

  // ---------------- Phase E: output projection (swapped) + float4 scatter ----------------
  {
    const ushort* W = wW + 3 * 16384;
    f32x4 acc[2][2] = {};
    for (int kk = 0; kk < 4; ++kk) {
      bf16x8 aw[2], bo[2];
#pragma unroll
      for (int mt = 0; mt < 2; ++mt)
        aw[mt] = *reinterpret_cast<const bf16x8*>(&W[(c0 + mt * 16 + lr) * 128 + kk * 32 + kg * 8]);
#pragma unroll
      for (int nt = 0; nt < 2; ++nt) {
        int tok = t0 + nt * 16 + lr; if (tok > 48) tok = 48;
        bo[nt] = *reinterpret_cast<const bf16x8*>(&lds[QS + tok * 136 + kk * 32 + kg * 8]);
      }
#pragma unroll
      for (int mt = 0; mt < 2; ++mt)
#pragma unroll
        for (int nt = 0; nt < 2; ++nt)
          acc[mt][nt] = __builtin_amdgcn_mfma_f32_16x16x32_bf16(aw[mt], bo[nt], acc[mt][nt], 0, 0, 0);
    }
#pragma unroll
    for (int mt = 0; mt < 2; ++mt) {
      float4 b4 = *reinterpret_cast<const float4*>(&wB[384 + c0 + mt * 16 + kg * 4]);
#pragma unroll
      for (int nt = 0; nt < 2; ++nt) {
        int tok = t0 + nt * 16 + lr;
        if (tok < 49) {
          int r = d7(tok), c = tok - r * 7;
          int gh = wi * 7 + r + SHF; if (gh >= IMG) gh -= IMG;
          int gw = wj * 7 + c + SHF; if (gw >= IMG) gw -= IMG;
          float4 o4 = { acc[mt][nt][0] + b4.x, acc[mt][nt][1] + b4.y,
                        acc[mt][nt][2] + b4.z, acc[mt][nt][3] + b4.w };
          *reinterpret_cast<float4*>(out + gBase + ((size_t)gh * IMG + gw) * 128 + c0 + mt * 16 + kg * 4) = o4;
        }
      }
    }
  }
}

extern "C" void kernel_launch(void* const* d_in, const int* in_sizes, int n_in,
                              void* d_out, int out_size, void* d_ws, size_t ws_size,
                              hipStream_t stream) {
  const float* X = (const float*)d_in[0];
  const float* Wq = (const float*)d_in[3];
  const float* Wk = (const float*)d_in[4];
  const float* Wv = (const float*)d_in[5];
  const float* Wp = (const float*)d_in[6];
  const float* bq = (const float*)d_in[7];
  const float* bk = (const float*)d_in[8];
  const float* bv = (const float*)d_in[9];
  const float* bp = (const float*)d_in[10];
  const float* tbl = (const float*)d_in[11];

  ushort* wW = (ushort*)d_ws;                             // 4 x [128][128] bf16 = 131072 B
  float* wB = (float*)((char*)d_ws + 131072);             // 4 x [128] f32   = 2048 B
  float* wRM = (float*)((char*)d_ws + 131072 + 2048);     // [4][4][64][64] f32 = 262144 B

  prep_kernel<<<dim3(514), dim3(256), 0, stream>>>(Wq, Wk, Wv, Wp, bq, bk, bv, bp, tbl, wW, wB, wRM);
  swin_kernel<<<dim3(8192), dim3(512), 0, stream>>>(X, wW, wB, wRM, (float*)d_out);
}